// Round 9
// baseline (444.732 us; speedup 1.0000x reference)
//
#include <hip/hip_runtime.h>
#include <hip/hip_bf16.h>

typedef __bf16 bf16x8 __attribute__((ext_vector_type(8)));
typedef float f32x4 __attribute__((ext_vector_type(4)));

__device__ __forceinline__ unsigned short f2bf(float f) {
  union { float f; unsigned u; } x; x.f = f;
  unsigned r = x.u + 0x7fffu + ((x.u >> 16) & 1u);
  return (unsigned short)(r >> 16);
}
__device__ __forceinline__ float bf2f(unsigned short u) {
  union { unsigned u; float f; } x; x.u = (unsigned)u << 16;
  return x.f;
}
__device__ __forceinline__ unsigned short f2h(float f) {
  union { _Float16 h; unsigned short u; } x; x.h = (_Float16)f;
  return x.u;
}
__device__ __forceinline__ float h2f(unsigned short u) {
  union { _Float16 h; unsigned short u; } x; x.u = u;
  return (float)x.h;
}

__device__ __forceinline__ void async_ld16(const void* g, void* l) {
  __builtin_amdgcn_global_load_lds(
      (__attribute__((address_space(1))) void*)const_cast<void*>(g),
      (__attribute__((address_space(3))) void*)l, 16, 0, 0);
}

// ------- 128x128 GEMM, r7 4-phase schedule, 2 independent blocks/CU -------
// BM=BN=128, BK=64, 256 thr (4 waves 2Mx2N), per-wave 64x64, acc[4][4].
// LDS 64KB: 2 dbuf x 4 parts {B-k0, A-k0, B-k1, A-k1}, part = [128 r][32 k]
// bf16 (8KB, 2 gload_lds/thread) -> 2 blocks/CU co-resident: while one block
// sits in its vmcnt/barrier window the other block's waves feed MFMA+LDS
// (m114 implicit cross-block overlap — the mechanism every 1-block/CU config
// of rounds 5-8 forfeited; all four stuck at 28-32% MfmaUtil).
// Schedule per K-tile (r7, dims halved): per kh: [vmcnt gate; s_barrier];
// read bfr(4); {read af(2); stage 1 part of t+1; setprio1; 8 MFMA; setprio0}
// x2 mh-halves.
// vmcnt ledger (2 loads/part, re-verified): prologue stages 4 parts (8 loads),
// vmcnt(4) -> Bk0,Ak0 landed. Entry (t,kh0): outstanding = t:{Bk0,Ak0,Bk1,Ak1}
// = 8 -> vmcnt(4) retires Bk0,Ak0(t). Entry (t,kh1): outstanding =
// {Bk1,Ak1(t), Bk0,Ak0(t+1)} = 8 -> vmcnt(4) retires Bk1,Ak1(t).
// Last tile (st=false): kh1 entry has only {Bk1,Ak1} -> vmcnt(0).
// WAR: stage of part(t+1) overwrites part(t-1), last read >=1 barrier ago.
// Swizzle (both-sides, r4-r8 verified 0 conflicts): slot-group g holds source
// k-group g ^ ((row>>1)&3); linear gload_lds dest + pre-swizzled global source
// + same XOR on ds_read.

#define EPI_F32    0
#define EPI_BF     1
#define EPI_RELUBF 2
#define EPI_F16    3

__global__ __launch_bounds__(256, 2) void gemm_bt(
    const unsigned short* __restrict__ A,   // [nb][M][K] bf16
    const unsigned short* __restrict__ Bt,  // [nb][N][K] bf16
    int M, int N, int K, int nbatch,
    long sA, long sB, long sC,
    float scale, int mode, void* __restrict__ outp)
{
  __shared__ unsigned short lds[32768];  // 64 KB
  const int t = threadIdx.x;
  const int w = t >> 6, l = t & 63;
  const int lr = l & 15, lg = l >> 4;
  const int wr = w >> 1, wc = w & 1;           // 2 M-waves x 2 N-waves
  const int ntn = N >> 7;                      // N/128
  const int tiles = (M >> 7) * ntn;            // per batch
  const int chunk = (tiles * nbatch) >> 3;
  const int bid = blockIdx.x;
  const int wg = (bid & 7) * chunk + (bid >> 3);
  const int batch = wg / tiles;
  const int rem = wg - batch * tiles;
  const int row0 = (rem / ntn) << 7;
  const int col0 = (rem % ntn) << 7;

  const unsigned short* Ab  = A  + (long)batch * sA;
  const unsigned short* Btb = Bt + (long)batch * sB;

  // ds_read swizzle slot (elems): frag k-group lg at slot lg ^ ((row>>1)&3);
  // (row>>1)&3 == (lr>>1)&3 for all frag rows (row = 16*m + lr, 16%8==0).
  const int ks = ((lg ^ ((lr >> 1) & 3)) << 3);

  // staging: thread covers row t>>2 (and +64 on 2nd load), dest group t&3;
  // source k-group = (t&3) ^ ((row>>1)&3) = (t&3) ^ ((t>>3)&3)  (64%4==0)
  const int srow = t >> 2;
  const int kgo  = (((t & 3) ^ ((t >> 3) & 3)) << 3);
  const long aoff0 = (long)(row0 + srow) * K + kgo;
  const long boff0 = (long)(col0 + srow) * K + kgo;
  const long off64 = (long)K << 6;

  const int NT = K >> 6;

#define STAGEP(partE, base, kcol)                                      \
  { async_ld16((base) + (kcol),         &lds[(partE) + t * 8]);        \
    async_ld16((base) + off64 + (kcol), &lds[(partE) + 2048 + t * 8]); }

  f32x4 acc[4][4];
#pragma unroll
  for (int m = 0; m < 4; ++m)
#pragma unroll
    for (int n = 0; n < 4; ++n) acc[m][n] = (f32x4){0.f, 0.f, 0.f, 0.f};

  // prologue: stage tile 0 (4 parts) into buf0; gate Bk0,Ak0
  STAGEP(0,     Btb + boff0, 0);
  STAGEP(4096,  Ab + aoff0,  0);
  STAGEP(8192,  Btb + boff0, 32);
  STAGEP(12288, Ab + aoff0,  32);
  __builtin_amdgcn_sched_barrier(0);

  for (int tt = 0; tt < NT; ++tt) {
    const int bufe  = (tt & 1) << 14;
    const int nbufe = ((tt + 1) & 1) << 14;
    const bool st = (tt + 1) < NT;
    const int kn = (tt + 1) << 6;

#pragma unroll
    for (int kh = 0; kh < 2; ++kh) {
      // ---- gate: this kh's parts must have landed
      if (kh == 0 || st) { asm volatile("s_waitcnt vmcnt(4)" ::: "memory"); }
      else               { asm volatile("s_waitcnt vmcnt(0)" ::: "memory"); }
      __builtin_amdgcn_sched_barrier(0);
      __builtin_amdgcn_s_barrier();
      __builtin_amdgcn_sched_barrier(0);

      const int pB = bufe + kh * 8192;
      const int pA = pB + 4096;

      bf16x8 bfr[4];
#pragma unroll
      for (int nf = 0; nf < 4; ++nf) {
        int rb = wc * 64 + nf * 16 + lr;
        bfr[nf] = *(const bf16x8*)&lds[pB + rb * 32 + ks];
      }
      // ---- phase (kh, mh0)
      {
        bf16x8 af[2];
#pragma unroll
        for (int i = 0; i < 2; ++i) {
          int ra = wr * 64 + i * 16 + lr;
          af[i] = *(const bf16x8*)&lds[pA + ra * 32 + ks];
        }
        if (st) STAGEP(nbufe + kh * 8192, Btb + boff0, kn + kh * 32);
        __builtin_amdgcn_s_setprio(1);
#pragma unroll
        for (int i = 0; i < 2; ++i)
#pragma unroll
          for (int nf = 0; nf < 4; ++nf)
            acc[i][nf] = __builtin_amdgcn_mfma_f32_16x16x32_bf16(af[i], bfr[nf], acc[i][nf], 0, 0, 0);
        __builtin_amdgcn_s_setprio(0);
      }
      // ---- phase (kh, mh1)
      {
        bf16x8 af[2];
#pragma unroll
        for (int i = 0; i < 2; ++i) {
          int ra = wr * 64 + (2 + i) * 16 + lr;
          af[i] = *(const bf16x8*)&lds[pA + ra * 32 + ks];
        }
        if (st) STAGEP(nbufe + kh * 8192 + 4096, Ab + aoff0, kn + kh * 32);
        __builtin_amdgcn_s_setprio(1);
#pragma unroll
        for (int i = 0; i < 2; ++i)
#pragma unroll
          for (int nf = 0; nf < 4; ++nf)
            acc[2 + i][nf] = __builtin_amdgcn_mfma_f32_16x16x32_bf16(af[i], bfr[nf], acc[2 + i][nf], 0, 0, 0);
        __builtin_amdgcn_s_setprio(0);
      }
      __builtin_amdgcn_sched_barrier(0);
    }
  }

  float* outF = (float*)outp;
  unsigned short* outH = (unsigned short*)outp;
  const size_t cb = (size_t)batch * (size_t)sC;
#pragma unroll
  for (int mf = 0; mf < 4; ++mf) {
    int rbase = row0 + wr * 64 + mf * 16 + lg * 4;
#pragma unroll
    for (int nf = 0; nf < 4; ++nf) {
      int c = col0 + wc * 64 + nf * 16 + lr;
      f32x4 v = acc[mf][nf];
#pragma unroll
      for (int q = 0; q < 4; ++q) {
        size_t idx = cb + (size_t)(rbase + q) * N + c;
        float val = v[q] * scale;
        if (mode == EPI_F32)         outF[idx] = val;
        else if (mode == EPI_BF)     outH[idx] = f2bf(val);
        else if (mode == EPI_RELUBF) outH[idx] = f2bf(fmaxf(val, 0.f));
        else                         outH[idx] = f2h(val);
      }
    }
  }
#undef STAGEP
}

// ---------------- elementwise / reduction kernels (unchanged) ----------------

__device__ __forceinline__ float wave_sum(float v) {
#pragma unroll
  for (int o = 32; o; o >>= 1) v += __shfl_xor(v, o, 64);
  return v;
}
__device__ __forceinline__ float wave_max(float v) {
#pragma unroll
  for (int o = 32; o; o >>= 1) v = fmaxf(v, __shfl_xor(v, o, 64));
  return v;
}

__global__ __launch_bounds__(256) void cast_bf16(const float* __restrict__ in,
                                                 unsigned short* __restrict__ out, long n) {
  long i = ((long)blockIdx.x * 256 + threadIdx.x) * 4;
  if (i >= n) return;
  float4 v = *(const float4*)&in[i];
  ushort4 o;
  o.x = f2bf(v.x); o.y = f2bf(v.y); o.z = f2bf(v.z); o.w = f2bf(v.w);
  *(ushort4*)&out[i] = o;
}

__global__ __launch_bounds__(256) void transpose_cast(const float* __restrict__ in,
                                                      unsigned short* __restrict__ out,
                                                      int R, int C) {
  __shared__ float tile[32][33];
  int c0 = blockIdx.x * 32, r0 = blockIdx.y * 32;
  int tx = threadIdx.x, ty = threadIdx.y;  // block (32,8)
  for (int i = ty; i < 32; i += 8) tile[i][tx] = in[(size_t)(r0 + i) * C + c0 + tx];
  __syncthreads();
  for (int i = ty; i < 32; i += 8) out[(size_t)(c0 + i) * R + r0 + tx] = f2bf(tile[tx][i]);
}

__global__ __launch_bounds__(256) void transpose_b16(const unsigned short* __restrict__ in,
                                                     unsigned short* __restrict__ out,
                                                     int R, int C) {
  __shared__ unsigned short tile[32][33];
  int c0 = blockIdx.x * 32, r0 = blockIdx.y * 32;
  size_t zb = (size_t)blockIdx.z * R * C;
  int tx = threadIdx.x, ty = threadIdx.y;  // block (32,8)
  for (int i = ty; i < 32; i += 8) tile[i][tx] = in[zb + (size_t)(r0 + i) * C + c0 + tx];
  __syncthreads();
  for (int i = ty; i < 32; i += 8) out[zb + (size_t)(c0 + i) * R + r0 + tx] = tile[tx][i];
}

__global__ __launch_bounds__(256) void softmax_rows(const unsigned short* __restrict__ g,
                                                    unsigned short* __restrict__ wout) {
  __shared__ float red[4];
  int row = blockIdx.x, t = threadIdx.x;
  const unsigned short* gr = g + ((size_t)row << 11) + t * 8;
  ushort4 ua = *(const ushort4*)gr;
  ushort4 ub = *(const ushort4*)(gr + 4);
  float a0 = h2f(ua.x), a1 = h2f(ua.y), a2 = h2f(ua.z), a3 = h2f(ua.w);
  float b0 = h2f(ub.x), b1 = h2f(ub.y), b2 = h2f(ub.z), b3 = h2f(ub.w);
  float mx = fmaxf(fmaxf(fmaxf(a0, a1), fmaxf(a2, a3)),
                   fmaxf(fmaxf(b0, b1), fmaxf(b2, b3)));
  mx = wave_max(mx);
  if ((t & 63) == 0) red[t >> 6] = mx;
  __syncthreads();
  mx = fmaxf(fmaxf(red[0], red[1]), fmaxf(red[2], red[3]));
  float e0 = __expf(a0 - mx), e1 = __expf(a1 - mx), e2 = __expf(a2 - mx), e3 = __expf(a3 - mx);
  float e4 = __expf(b0 - mx), e5 = __expf(b1 - mx), e6 = __expf(b2 - mx), e7 = __expf(b3 - mx);
  float s = ((e0 + e1) + (e2 + e3)) + ((e4 + e5) + (e6 + e7));
  s = wave_sum(s);
  __syncthreads();
  if ((t & 63) == 0) red[t >> 6] = s;
  __syncthreads();
  s = (red[0] + red[1]) + (red[2] + red[3]);
  float inv = 1.0f / s;
  ushort4 o0, o1;
  o0.x = f2bf(e0 * inv); o0.y = f2bf(e1 * inv); o0.z = f2bf(e2 * inv); o0.w = f2bf(e3 * inv);
  o1.x = f2bf(e4 * inv); o1.y = f2bf(e5 * inv); o1.z = f2bf(e6 * inv); o1.w = f2bf(e7 * inv);
  size_t base = ((size_t)row << 11) + t * 8;
  *(ushort4*)&wout[base] = o0;
  *(ushort4*)&wout[base + 4] = o1;
}

__global__ __launch_bounds__(256) void ln_residual_bf(const unsigned short* __restrict__ xb,
                                                      const float* __restrict__ attn,
                                                      unsigned short* __restrict__ outB) {
  __shared__ float red[4];
  int row = blockIdx.x, t = threadIdx.x;
  size_t base = ((size_t)row << 10) + t * 4;
  ushort4 ua = *(const ushort4*)&xb[base];
  float4 vb = *(const float4*)&attn[base];
  float4 v = {bf2f(ua.x) + vb.x, bf2f(ua.y) + vb.y, bf2f(ua.z) + vb.z, bf2f(ua.w) + vb.w};
  float s = (v.x + v.y) + (v.z + v.w);
  float ss = (v.x * v.x + v.y * v.y) + (v.z * v.z + v.w * v.w);
  s = wave_sum(s);
  if ((t & 63) == 0) red[t >> 6] = s;
  __syncthreads();
  s = (red[0] + red[1]) + (red[2] + red[3]);
  ss = wave_sum(ss);
  __syncthreads();
  if ((t & 63) == 0) red[t >> 6] = ss;
  __syncthreads();
  ss = (red[0] + red[1]) + (red[2] + red[3]);
  float mean = s * (1.0f / 1024.0f);
  float var = (ss - s * mean) * (1.0f / 1023.0f);
  float rstd = rsqrtf(var);
  ushort4 ob;
  ob.x = f2bf((v.x - mean) * rstd); ob.y = f2bf((v.y - mean) * rstd);
  ob.z = f2bf((v.z - mean) * rstd); ob.w = f2bf((v.w - mean) * rstd);
  *(ushort4*)&outB[base] = ob;
}

__global__ __launch_bounds__(256) void ln_residual_dot(const unsigned short* __restrict__ h2,
                                                       const unsigned short* __restrict__ post,
                                                       const float* __restrict__ readout,
                                                       float* __restrict__ rowdot) {
  __shared__ float red[4];
  int row = blockIdx.x, t = threadIdx.x;
  size_t base = ((size_t)row << 10) + t * 4;
  ushort4 ua = *(const ushort4*)&h2[base];
  ushort4 ub = *(const ushort4*)&post[base];
  float4 v = {bf2f(ua.x) + bf2f(ub.x), bf2f(ua.y) + bf2f(ub.y),
              bf2f(ua.z) + bf2f(ub.z), bf2f(ua.w) + bf2f(ub.w)};
  float s = (v.x + v.y) + (v.z + v.w);
  float ss = (v.x * v.x + v.y * v.y) + (v.z * v.z + v.w * v.w);
  s = wave_sum(s);
  if ((t & 63) == 0) red[t >> 6] = s;
  __syncthreads();
  s = (red[0] + red[1]) + (red[2] + red[3]);
  ss = wave_sum(ss);
  __syncthreads();
  if ((t & 63) == 0) red[t >> 6] = ss;
  __syncthreads();
  ss = (red[0] + red[1]) + (red[2] + red[3]);
  float mean = s * (1.0f / 1024.0f);
  float var = (ss - s * mean) * (1.0f / 1023.0f);
  float rstd = rsqrtf(var);
  float4 r = *(const float4*)&readout[t * 4];
  float dot = (v.x - mean) * rstd * r.x + (v.y - mean) * rstd * r.y +
              (v.z - mean) * rstd * r.z + (v.w - mean) * rstd * r.w;
  dot = wave_sum(dot);
  __syncthreads();
  if ((t & 63) == 0) red[t >> 6] = dot;
  __syncthreads();
  if (t == 0) rowdot[row] = (red[0] + red[1]) + (red[2] + red[3]);
}

__global__ __launch_bounds__(256) void reduce_out(const float* __restrict__ rowdot,
                                                  float* __restrict__ out) {
  __shared__ float red[4];
  int b = blockIdx.x, t = threadIdx.x;
  float s = 0.f;
  for (int i = t; i < 2048; i += 256) s += rowdot[(size_t)b * 2048 + i];
  s = wave_sum(s);
  if ((t & 63) == 0) red[t >> 6] = s;
  __syncthreads();
  if (t == 0) out[b] = ((red[0] + red[1]) + (red[2] + red[3])) * (1.0f / 65536.0f);
}

extern "C" void kernel_launch(void* const* d_in, const int* in_sizes, int n_in,
                              void* d_out, int out_size, void* d_ws, size_t ws_size,
                              hipStream_t stream) {
  const float* seq     = (const float*)d_in[0];  // [8,2048,768]
  const float* emb     = (const float*)d_in[1];  // [768,1024]
  const float* W1      = (const float*)d_in[2];  // [1024,1024]
  const float* W2      = (const float*)d_in[3];  // [1024,1024]
  const float* readout = (const float*)d_in[4];  // [1024]
  float* out = (float*)d_out;                    // [8]

  char* ws = (char*)d_ws;
  const size_t MB = 1024u * 1024u;
  // aliased layout (verified rounds 3-8):
  unsigned short* x_b    = (unsigned short*)(ws + 0);        // 32MB [G1..LN1]
  unsigned short* h2b    = (unsigned short*)(ws + 0);        // 32MB [FFN2..LN2]
  unsigned short* xT     = (unsigned short*)(ws + 32 * MB);  // 32MB [tr..attnV]
  unsigned short* hrelu  = (unsigned short*)(ws + 32 * MB);  // 32MB [FFN1..FFN2]
  unsigned short* gram   = (unsigned short*)(ws + 64 * MB);  // 64MB f16 [G2..sm]
  float*          attn   = (float*)(ws + 64 * MB);           // 64MB [aV..LN1]
  unsigned short* wts    = (unsigned short*)(ws + 128 * MB); // 64MB [sm..attnV]
  unsigned short* post_b = (unsigned short*)(ws + 128 * MB); // 32MB [LN1..LN2]
  unsigned short* seq_b  = (unsigned short*)(ws + 192 * MB); // 24MB [cast..G1]
  unsigned short* embT   = (unsigned short*)(ws + 216 * MB);
  unsigned short* W1T    = (unsigned short*)(ws + 218 * MB);
  unsigned short* W2T    = (unsigned short*)(ws + 220 * MB);
  float*          rowdot = (float*)(ws + 222 * MB);

  // 1. dtype prep
  cast_bf16<<<12288, 256, 0, stream>>>(seq, seq_b, 12582912L);
  transpose_cast<<<dim3(32, 24), dim3(32, 8), 0, stream>>>(emb, embT, 768, 1024);
  transpose_cast<<<dim3(32, 32), dim3(32, 8), 0, stream>>>(W1, W1T, 1024, 1024);
  transpose_cast<<<dim3(32, 32), dim3(32, 8), 0, stream>>>(W2, W2T, 1024, 1024);

  // 2. x = seq @ emb / sqrt(768)  -> bf16   (grid = 128*8 = 1024)
  gemm_bt<<<1024, 256, 0, stream>>>(seq_b, embT, 16384, 1024, 768, 1, 0, 0, 0,
                                    0.03608439182435161f, EPI_BF, x_b);

  // 3. xT[b] = x[b]^T
  transpose_b16<<<dim3(32, 64, 8), dim3(32, 8), 0, stream>>>(x_b, xT, 2048, 1024);

  // 4. gram[b] = x[b] @ x[b]^T / 1024 -> f16  (grid = 8*16*16 = 2048)
  gemm_bt<<<2048, 256, 0, stream>>>(x_b, x_b, 2048, 2048, 1024, 8,
                                    2048L * 1024, 2048L * 1024, 2048L * 2048,
                                    1.0f / 1024.0f, EPI_F16, gram);

  // 5. weights = softmax(gram) -> bf16
  softmax_rows<<<16384, 256, 0, stream>>>(gram, wts);

  // 6. attn[b] = weights[b] @ x[b] -> f32  (grid = 8*16*8 = 1024)
  gemm_bt<<<1024, 256, 0, stream>>>(wts, xT, 2048, 1024, 2048, 8,
                                    2048L * 2048, 1024L * 2048, 2048L * 1024,
                                    1.0f, EPI_F32, attn);

  // 7. post = LN(x + attn) -> bf16
  ln_residual_bf<<<16384, 256, 0, stream>>>(x_b, attn, post_b);

  // 8. FFN (grids 128*8 = 1024)
  gemm_bt<<<1024, 256, 0, stream>>>(post_b, W1T, 16384, 1024, 1024, 1, 0, 0, 0,
                                    0.03125f, EPI_RELUBF, hrelu);
  gemm_bt<<<1024, 256, 0, stream>>>(hrelu, W2T, 16384, 1024, 1024, 1, 0, 0, 0,
                                    0.03125f, EPI_BF, h2b);

  // 9. final LN + pooled readout
  ln_residual_dot<<<16384, 256, 0, stream>>>(h2b, post_b, readout, rowdot);
  reduce_out<<<8, 256, 0, stream>>>(rowdot, out);
}

// Round 10
// 368.453 us; speedup vs baseline: 1.2070x; 1.2070x over previous
//
#include <hip/hip_runtime.h>
#include <hip/hip_bf16.h>

typedef __bf16 bf16x8 __attribute__((ext_vector_type(8)));
typedef float f32x4 __attribute__((ext_vector_type(4)));

__device__ __forceinline__ unsigned short f2bf(float f) {
  union { float f; unsigned u; } x; x.f = f;
  unsigned r = x.u + 0x7fffu + ((x.u >> 16) & 1u);
  return (unsigned short)(r >> 16);
}
__device__ __forceinline__ float bf2f(unsigned short u) {
  union { unsigned u; float f; } x; x.u = (unsigned)u << 16;
  return x.f;
}
__device__ __forceinline__ unsigned short f2h(float f) {
  union { _Float16 h; unsigned short u; } x; x.h = (_Float16)f;
  return x.u;
}
__device__ __forceinline__ float h2f(unsigned short u) {
  union { _Float16 h; unsigned short u; } x; x.u = u;
  return (float)x.h;
}

__device__ __forceinline__ void async_ld16(const void* g, void* l) {
  __builtin_amdgcn_global_load_lds(
      (__attribute__((address_space(1))) void*)const_cast<void*>(g),
      (__attribute__((address_space(3))) void*)l, 16, 0, 0);
}

// ---- r7 GEMM (best measured): 256x256, 4-phase K-split, 2 gates/K-tile ----
// BM=BN=256, BK=64, 512 thr (8 waves 2Mx4N), per-wave 128x64, acc[8][4].
// LDS 128KB: 2 dbuf x 4 parts {B-k0,A-k0,B-k1,A-k1}, part=[256r][32k] bf16.
// Gates: vmcnt(4)+s_barrier at kh entries (ledger verified r7).
// Swizzle (both-sides, 0 conflicts r4-r9): slot-group g = srcgrp ^ ((row>>1)&3).

#define EPI_F32    0
#define EPI_BF     1
#define EPI_RELUBF 2
#define EPI_F16    3

__global__ __launch_bounds__(512, 2) void gemm_bt(
    const unsigned short* __restrict__ A,   // [nb][M][K] bf16
    const unsigned short* __restrict__ Bt,  // [nb][N][K] bf16
    int M, int N, int K, int nbatch,
    long sA, long sB, long sC,
    float scale, int mode, void* __restrict__ outp)
{
  __shared__ unsigned short lds[65536];  // 128 KB
  const int t = threadIdx.x;
  const int w = t >> 6, l = t & 63;
  const int lr = l & 15, lg = l >> 4;
  const int wr = w >> 2, wc = w & 3;           // 2 M-waves x 4 N-waves
  const int ntn = N >> 8;
  const int tiles = (M >> 8) * ntn;
  const int chunk = (tiles * nbatch) >> 3;
  const int bid = blockIdx.x;
  const int wg = (bid & 7) * chunk + (bid >> 3);
  const int batch = wg / tiles;
  const int rem = wg - batch * tiles;
  const int row0 = (rem / ntn) << 8;
  const int col0 = (rem % ntn) << 8;

  const unsigned short* Ab  = A  + (long)batch * sA;
  const unsigned short* Btb = Bt + (long)batch * sB;

  const int ks = ((lg ^ ((lr >> 1) & 3)) << 3);

  const int srow = w * 16 + (l >> 2);
  const int kgo  = (((l & 3) ^ ((l >> 3) & 3)) << 3);
  const long aoff0 = (long)(row0 + srow) * K + kgo;
  const long boff0 = (long)(col0 + srow) * K + kgo;
  const long off128 = (long)K << 7;

  const int NT = K >> 6;

#define STAGEP(partE, base, kcol)                                      \
  { async_ld16((base) + (kcol),          &lds[(partE) + t * 8]);       \
    async_ld16((base) + off128 + (kcol), &lds[(partE) + 4096 + t * 8]); }

  f32x4 acc[8][4];
#pragma unroll
  for (int m = 0; m < 8; ++m)
#pragma unroll
    for (int n = 0; n < 4; ++n) acc[m][n] = (f32x4){0.f, 0.f, 0.f, 0.f};

  STAGEP(0,     Btb + boff0, 0);
  STAGEP(8192,  Ab + aoff0,  0);
  STAGEP(16384, Btb + boff0, 32);
  STAGEP(24576, Ab + aoff0,  32);
  __builtin_amdgcn_sched_barrier(0);

  for (int tt = 0; tt < NT; ++tt) {
    const int bufe  = (tt & 1) << 15;
    const int nbufe = ((tt + 1) & 1) << 15;
    const bool st = (tt + 1) < NT;
    const int kn = (tt + 1) << 6;

#pragma unroll
    for (int kh = 0; kh < 2; ++kh) {
      if (kh == 0 || st) { asm volatile("s_waitcnt vmcnt(4)" ::: "memory"); }
      else               { asm volatile("s_waitcnt vmcnt(0)" ::: "memory"); }
      __builtin_amdgcn_sched_barrier(0);
      __builtin_amdgcn_s_barrier();
      __builtin_amdgcn_sched_barrier(0);

      const int pB = bufe + kh * 16384;
      const int pA = pB + 8192;

      bf16x8 bfr[4];
#pragma unroll
      for (int nf = 0; nf < 4; ++nf) {
        int rb = wc * 64 + nf * 16 + lr;
        bfr[nf] = *(const bf16x8*)&lds[pB + rb * 32 + ks];
      }
      {
        bf16x8 af[4];
#pragma unroll
        for (int i = 0; i < 4; ++i) {
          int ra = wr * 128 + i * 16 + lr;
          af[i] = *(const bf16x8*)&lds[pA + ra * 32 + ks];
        }
        if (st) STAGEP(nbufe + kh * 16384, Btb + boff0, kn + kh * 32);
        __builtin_amdgcn_s_setprio(1);
#pragma unroll
        for (int i = 0; i < 4; ++i)
#pragma unroll
          for (int nf = 0; nf < 4; ++nf)
            acc[i][nf] = __builtin_amdgcn_mfma_f32_16x16x32_bf16(af[i], bfr[nf], acc[i][nf], 0, 0, 0);
        __builtin_amdgcn_s_setprio(0);
      }
      {
        bf16x8 af[4];
#pragma unroll
        for (int i = 0; i < 4; ++i) {
          int ra = wr * 128 + 64 + i * 16 + lr;
          af[i] = *(const bf16x8*)&lds[pA + ra * 32 + ks];
        }
        if (st) STAGEP(nbufe + kh * 16384 + 8192, Ab + aoff0, kn + kh * 32);
        __builtin_amdgcn_s_setprio(1);
#pragma unroll
        for (int i = 0; i < 4; ++i)
#pragma unroll
          for (int nf = 0; nf < 4; ++nf)
            acc[4 + i][nf] = __builtin_amdgcn_mfma_f32_16x16x32_bf16(af[i], bfr[nf], acc[4 + i][nf], 0, 0, 0);
        __builtin_amdgcn_s_setprio(0);
      }
      __builtin_amdgcn_sched_barrier(0);
    }
  }

  float* outF = (float*)outp;
  unsigned short* outH = (unsigned short*)outp;
  const size_t cb = (size_t)batch * (size_t)sC;
#pragma unroll
  for (int mf = 0; mf < 8; ++mf) {
    int rbase = row0 + wr * 128 + mf * 16 + lg * 4;
#pragma unroll
    for (int nf = 0; nf < 4; ++nf) {
      int c = col0 + wc * 64 + nf * 16 + lr;
      f32x4 v = acc[mf][nf];
#pragma unroll
      for (int q = 0; q < 4; ++q) {
        size_t idx = cb + (size_t)(rbase + q) * N + c;
        float val = v[q] * scale;
        if (mode == EPI_F32)         outF[idx] = val;
        else if (mode == EPI_BF)     outH[idx] = f2bf(val);
        else if (mode == EPI_RELUBF) outH[idx] = f2bf(fmaxf(val, 0.f));
        else                         outH[idx] = f2h(val);
      }
    }
  }
#undef STAGEP
}

// ---- symmetric gram: gram[b] = x[b] @ x[b]^T / 1024 -> f16, upper tiles only.
// Same r7 schedule, S=2048, D=1024 fixed. 36 triangular tiles/batch, grid 288
// (chunk 36 = one batch per XCD). Off-diagonal tiles also write the mirrored
// tile: lane's v[q] (rows rbase..+3, col c) -> out[c][rbase..+3] as one 8B
// ushort4 store (16 consecutive r per lg-group => 32B segments).
__global__ __launch_bounds__(512, 2) void gram_sym(
    const unsigned short* __restrict__ X,   // [8][2048][1024] bf16
    unsigned short* __restrict__ outH)      // [8][2048][2048] f16
{
  __shared__ unsigned short lds[65536];
  const int t = threadIdx.x;
  const int w = t >> 6, l = t & 63;
  const int lr = l & 15, lg = l >> 4;
  const int wr = w >> 2, wc = w & 3;
  const int bid = blockIdx.x;
  const int wg = (bid & 7) * 36 + (bid >> 3);
  const int batch = wg / 36;
  int r8 = wg - batch * 36;
  int bi = 0;
  while (r8 >= 8 - bi) { r8 -= 8 - bi; ++bi; }
  const int bj = bi + r8;
  const int row0 = bi << 8;
  const int col0 = bj << 8;

  const unsigned short* Xb = X + (long)batch * 2048 * 1024;

  const int ks = ((lg ^ ((lr >> 1) & 3)) << 3);
  const int srow = w * 16 + (l >> 2);
  const int kgo  = (((l & 3) ^ ((l >> 3) & 3)) << 3);
  const long aoff0 = (long)(row0 + srow) * 1024 + kgo;
  const long boff0 = (long)(col0 + srow) * 1024 + kgo;
  const long off128 = 1024L << 7;

#define STAGEP(partE, base, kcol)                                      \
  { async_ld16((base) + (kcol),          &lds[(partE) + t * 8]);       \
    async_ld16((base) + off128 + (kcol), &lds[(partE) + 4096 + t * 8]); }

  f32x4 acc[8][4];
#pragma unroll
  for (int m = 0; m < 8; ++m)
#pragma unroll
    for (int n = 0; n < 4; ++n) acc[m][n] = (f32x4){0.f, 0.f, 0.f, 0.f};

  STAGEP(0,     Xb + boff0, 0);
  STAGEP(8192,  Xb + aoff0,  0);
  STAGEP(16384, Xb + boff0, 32);
  STAGEP(24576, Xb + aoff0,  32);
  __builtin_amdgcn_sched_barrier(0);

  for (int tt = 0; tt < 16; ++tt) {
    const int bufe  = (tt & 1) << 15;
    const int nbufe = ((tt + 1) & 1) << 15;
    const bool st = (tt + 1) < 16;
    const int kn = (tt + 1) << 6;

#pragma unroll
    for (int kh = 0; kh < 2; ++kh) {
      if (kh == 0 || st) { asm volatile("s_waitcnt vmcnt(4)" ::: "memory"); }
      else               { asm volatile("s_waitcnt vmcnt(0)" ::: "memory"); }
      __builtin_amdgcn_sched_barrier(0);
      __builtin_amdgcn_s_barrier();
      __builtin_amdgcn_sched_barrier(0);

      const int pB = bufe + kh * 16384;
      const int pA = pB + 8192;

      bf16x8 bfr[4];
#pragma unroll
      for (int nf = 0; nf < 4; ++nf) {
        int rb = wc * 64 + nf * 16 + lr;
        bfr[nf] = *(const bf16x8*)&lds[pB + rb * 32 + ks];
      }
      {
        bf16x8 af[4];
#pragma unroll
        for (int i = 0; i < 4; ++i) {
          int ra = wr * 128 + i * 16 + lr;
          af[i] = *(const bf16x8*)&lds[pA + ra * 32 + ks];
        }
        if (st) STAGEP(nbufe + kh * 16384, Xb + boff0, kn + kh * 32);
        __builtin_amdgcn_s_setprio(1);
#pragma unroll
        for (int i = 0; i < 4; ++i)
#pragma unroll
          for (int nf = 0; nf < 4; ++nf)
            acc[i][nf] = __builtin_amdgcn_mfma_f32_16x16x32_bf16(af[i], bfr[nf], acc[i][nf], 0, 0, 0);
        __builtin_amdgcn_s_setprio(0);
      }
      {
        bf16x8 af[4];
#pragma unroll
        for (int i = 0; i < 4; ++i) {
          int ra = wr * 128 + 64 + i * 16 + lr;
          af[i] = *(const bf16x8*)&lds[pA + ra * 32 + ks];
        }
        if (st) STAGEP(nbufe + kh * 16384 + 8192, Xb + aoff0, kn + kh * 32);
        __builtin_amdgcn_s_setprio(1);
#pragma unroll
        for (int i = 0; i < 4; ++i)
#pragma unroll
          for (int nf = 0; nf < 4; ++nf)
            acc[4 + i][nf] = __builtin_amdgcn_mfma_f32_16x16x32_bf16(af[i], bfr[nf], acc[4 + i][nf], 0, 0, 0);
        __builtin_amdgcn_s_setprio(0);
      }
      __builtin_amdgcn_sched_barrier(0);
    }
  }

  unsigned short* ob = outH + (size_t)batch * 2048 * 2048;
  const float scale = 1.0f / 1024.0f;
  const bool mirror = (bi != bj);
#pragma unroll
  for (int mf = 0; mf < 8; ++mf) {
    int rbase = row0 + wr * 128 + mf * 16 + lg * 4;
#pragma unroll
    for (int nf = 0; nf < 4; ++nf) {
      int c = col0 + wc * 64 + nf * 16 + lr;
      f32x4 v = acc[mf][nf];
      unsigned short h0 = f2h(v[0] * scale), h1 = f2h(v[1] * scale);
      unsigned short h2 = f2h(v[2] * scale), h3 = f2h(v[3] * scale);
      ob[(size_t)(rbase + 0) * 2048 + c] = h0;
      ob[(size_t)(rbase + 1) * 2048 + c] = h1;
      ob[(size_t)(rbase + 2) * 2048 + c] = h2;
      ob[(size_t)(rbase + 3) * 2048 + c] = h3;
      if (mirror) {
        ushort4 m4 = {h0, h1, h2, h3};
        *(ushort4*)&ob[(size_t)c * 2048 + rbase] = m4;
      }
    }
  }
#undef STAGEP
}

// ---------------- elementwise / reduction kernels ----------------

__device__ __forceinline__ float wave_sum(float v) {
#pragma unroll
  for (int o = 32; o; o >>= 1) v += __shfl_xor(v, o, 64);
  return v;
}
__device__ __forceinline__ float wave_max(float v) {
#pragma unroll
  for (int o = 32; o; o >>= 1) v = fmaxf(v, __shfl_xor(v, o, 64));
  return v;
}

__global__ __launch_bounds__(256) void cast_bf16(const float* __restrict__ in,
                                                 unsigned short* __restrict__ out, long n) {
  long i = ((long)blockIdx.x * 256 + threadIdx.x) * 4;
  if (i >= n) return;
  float4 v = *(const float4*)&in[i];
  ushort4 o;
  o.x = f2bf(v.x); o.y = f2bf(v.y); o.z = f2bf(v.z); o.w = f2bf(v.w);
  *(ushort4*)&out[i] = o;
}

__global__ __launch_bounds__(256) void transpose_cast(const float* __restrict__ in,
                                                      unsigned short* __restrict__ out,
                                                      int R, int C) {
  __shared__ float tile[32][33];
  int c0 = blockIdx.x * 32, r0 = blockIdx.y * 32;
  int tx = threadIdx.x, ty = threadIdx.y;  // block (32,8)
  for (int i = ty; i < 32; i += 8) tile[i][tx] = in[(size_t)(r0 + i) * C + c0 + tx];
  __syncthreads();
  for (int i = ty; i < 32; i += 8) out[(size_t)(c0 + i) * R + r0 + tx] = f2bf(tile[tx][i]);
}

__global__ __launch_bounds__(256) void transpose_b16(const unsigned short* __restrict__ in,
                                                     unsigned short* __restrict__ out,
                                                     int R, int C) {
  __shared__ unsigned short tile[32][33];
  int c0 = blockIdx.x * 32, r0 = blockIdx.y * 32;
  size_t zb = (size_t)blockIdx.z * R * C;
  int tx = threadIdx.x, ty = threadIdx.y;  // block (32,8)
  for (int i = ty; i < 32; i += 8) tile[i][tx] = in[zb + (size_t)(r0 + i) * C + c0 + tx];
  __syncthreads();
  for (int i = ty; i < 32; i += 8) out[zb + (size_t)(c0 + i) * R + r0 + tx] = tile[tx][i];
}

__global__ __launch_bounds__(256) void softmax_rows(const unsigned short* __restrict__ g,
                                                    unsigned short* __restrict__ wout) {
  __shared__ float red[4];
  int row = blockIdx.x, t = threadIdx.x;
  const unsigned short* gr = g + ((size_t)row << 11) + t * 8;
  ushort4 ua = *(const ushort4*)gr;
  ushort4 ub = *(const ushort4*)(gr + 4);
  float a0 = h2f(ua.x), a1 = h2f(ua.y), a2 = h2f(ua.z), a3 = h2f(ua.w);
  float b0 = h2f(ub.x), b1 = h2f(ub.y), b2 = h2f(ub.z), b3 = h2f(ub.w);
  float mx = fmaxf(fmaxf(fmaxf(a0, a1), fmaxf(a2, a3)),
                   fmaxf(fmaxf(b0, b1), fmaxf(b2, b3)));
  mx = wave_max(mx);
  if ((t & 63) == 0) red[t >> 6] = mx;
  __syncthreads();
  mx = fmaxf(fmaxf(red[0], red[1]), fmaxf(red[2], red[3]));
  float e0 = __expf(a0 - mx), e1 = __expf(a1 - mx), e2 = __expf(a2 - mx), e3 = __expf(a3 - mx);
  float e4 = __expf(b0 - mx), e5 = __expf(b1 - mx), e6 = __expf(b2 - mx), e7 = __expf(b3 - mx);
  float s = ((e0 + e1) + (e2 + e3)) + ((e4 + e5) + (e6 + e7));
  s = wave_sum(s);
  __syncthreads();
  if ((t & 63) == 0) red[t >> 6] = s;
  __syncthreads();
  s = (red[0] + red[1]) + (red[2] + red[3]);
  float inv = 1.0f / s;
  ushort4 o0, o1;
  o0.x = f2bf(e0 * inv); o0.y = f2bf(e1 * inv); o0.z = f2bf(e2 * inv); o0.w = f2bf(e3 * inv);
  o1.x = f2bf(e4 * inv); o1.y = f2bf(e5 * inv); o1.z = f2bf(e6 * inv); o1.w = f2bf(e7 * inv);
  size_t base = ((size_t)row << 11) + t * 8;
  *(ushort4*)&wout[base] = o0;
  *(ushort4*)&wout[base + 4] = o1;
}

// post = LN(x_b + attn_b), both bf16
__global__ __launch_bounds__(256) void ln_residual_bb(const unsigned short* __restrict__ xb,
                                                      const unsigned short* __restrict__ ab,
                                                      unsigned short* __restrict__ outB) {
  __shared__ float red[4];
  int row = blockIdx.x, t = threadIdx.x;
  size_t base = ((size_t)row << 10) + t * 4;
  ushort4 ua = *(const ushort4*)&xb[base];
  ushort4 ub = *(const ushort4*)&ab[base];
  float4 v = {bf2f(ua.x) + bf2f(ub.x), bf2f(ua.y) + bf2f(ub.y),
              bf2f(ua.z) + bf2f(ub.z), bf2f(ua.w) + bf2f(ub.w)};
  float s = (v.x + v.y) + (v.z + v.w);
  float ss = (v.x * v.x + v.y * v.y) + (v.z * v.z + v.w * v.w);
  s = wave_sum(s);
  if ((t & 63) == 0) red[t >> 6] = s;
  __syncthreads();
  s = (red[0] + red[1]) + (red[2] + red[3]);
  ss = wave_sum(ss);
  __syncthreads();
  if ((t & 63) == 0) red[t >> 6] = ss;
  __syncthreads();
  ss = (red[0] + red[1]) + (red[2] + red[3]);
  float mean = s * (1.0f / 1024.0f);
  float var = (ss - s * mean) * (1.0f / 1023.0f);
  float rstd = rsqrtf(var);
  ushort4 ob;
  ob.x = f2bf((v.x - mean) * rstd); ob.y = f2bf((v.y - mean) * rstd);
  ob.z = f2bf((v.z - mean) * rstd); ob.w = f2bf((v.w - mean) * rstd);
  *(ushort4*)&outB[base] = ob;
}

__global__ __launch_bounds__(256) void ln_residual_dot(const unsigned short* __restrict__ h2,
                                                       const unsigned short* __restrict__ post,
                                                       const float* __restrict__ readout,
                                                       float* __restrict__ rowdot) {
  __shared__ float red[4];
  int row = blockIdx.x, t = threadIdx.x;
  size_t base = ((size_t)row << 10) + t * 4;
  ushort4 ua = *(const ushort4*)&h2[base];
  ushort4 ub = *(const ushort4*)&post[base];
  float4 v = {bf2f(ua.x) + bf2f(ub.x), bf2f(ua.y) + bf2f(ub.y),
              bf2f(ua.z) + bf2f(ub.z), bf2f(ua.w) + bf2f(ub.w)};
  float s = (v.x + v.y) + (v.z + v.w);
  float ss = (v.x * v.x + v.y * v.y) + (v.z * v.z + v.w * v.w);
  s = wave_sum(s);
  if ((t & 63) == 0) red[t >> 6] = s;
  __syncthreads();
  s = (red[0] + red[1]) + (red[2] + red[3]);
  ss = wave_sum(ss);
  __syncthreads();
  if ((t & 63) == 0) red[t >> 6] = ss;
  __syncthreads();
  ss = (red[0] + red[1]) + (red[2] + red[3]);
  float mean = s * (1.0f / 1024.0f);
  float var = (ss - s * mean) * (1.0f / 1023.0f);
  float rstd = rsqrtf(var);
  float4 r = *(const float4*)&readout[t * 4];
  float dot = (v.x - mean) * rstd * r.x + (v.y - mean) * rstd * r.y +
              (v.z - mean) * rstd * r.z + (v.w - mean) * rstd * r.w;
  dot = wave_sum(dot);
  __syncthreads();
  if ((t & 63) == 0) red[t >> 6] = dot;
  __syncthreads();
  if (t == 0) rowdot[row] = (red[0] + red[1]) + (red[2] + red[3]);
}

__global__ __launch_bounds__(256) void reduce_out(const float* __restrict__ rowdot,
                                                  float* __restrict__ out) {
  __shared__ float red[4];
  int b = blockIdx.x, t = threadIdx.x;
  float s = 0.f;
  for (int i = t; i < 2048; i += 256) s += rowdot[(size_t)b * 2048 + i];
  s = wave_sum(s);
  if ((t & 63) == 0) red[t >> 6] = s;
  __syncthreads();
  if (t == 0) out[b] = ((red[0] + red[1]) + (red[2] + red[3])) * (1.0f / 65536.0f);
}

extern "C" void kernel_launch(void* const* d_in, const int* in_sizes, int n_in,
                              void* d_out, int out_size, void* d_ws, size_t ws_size,
                              hipStream_t stream) {
  const float* seq     = (const float*)d_in[0];  // [8,2048,768]
  const float* emb     = (const float*)d_in[1];  // [768,1024]
  const float* W1      = (const float*)d_in[2];  // [1024,1024]
  const float* W2      = (const float*)d_in[3];  // [1024,1024]
  const float* readout = (const float*)d_in[4];  // [1024]
  float* out = (float*)d_out;                    // [8]

  char* ws = (char*)d_ws;
  const size_t MB = 1024u * 1024u;
  // aliased layout (verified rounds 3-9; attn now bf16 32MB):
  unsigned short* x_b    = (unsigned short*)(ws + 0);        // 32MB [G1..LN1]
  unsigned short* h2b    = (unsigned short*)(ws + 0);        // 32MB [FFN2..LN2]
  unsigned short* xT     = (unsigned short*)(ws + 32 * MB);  // 32MB [tr..attnV]
  unsigned short* hrelu  = (unsigned short*)(ws + 32 * MB);  // 32MB [FFN1..FFN2]
  unsigned short* gram   = (unsigned short*)(ws + 64 * MB);  // 64MB f16 [G2..sm]
  unsigned short* attn_b = (unsigned short*)(ws + 64 * MB);  // 32MB bf16 [aV..LN1]
  unsigned short* wts    = (unsigned short*)(ws + 128 * MB); // 64MB [sm..attnV]
  unsigned short* post_b = (unsigned short*)(ws + 128 * MB); // 32MB [LN1..LN2]
  unsigned short* seq_b  = (unsigned short*)(ws + 192 * MB); // 24MB [cast..G1]
  unsigned short* embT   = (unsigned short*)(ws + 216 * MB);
  unsigned short* W1T    = (unsigned short*)(ws + 218 * MB);
  unsigned short* W2T    = (unsigned short*)(ws + 220 * MB);
  float*          rowdot = (float*)(ws + 222 * MB);

  // 1. dtype prep
  cast_bf16<<<12288, 256, 0, stream>>>(seq, seq_b, 12582912L);
  transpose_cast<<<dim3(32, 24), dim3(32, 8), 0, stream>>>(emb, embT, 768, 1024);
  transpose_cast<<<dim3(32, 32), dim3(32, 8), 0, stream>>>(W1, W1T, 1024, 1024);
  transpose_cast<<<dim3(32, 32), dim3(32, 8), 0, stream>>>(W2, W2T, 1024, 1024);

  // 2. x = seq @ emb / sqrt(768)  -> bf16
  gemm_bt<<<256, 512, 0, stream>>>(seq_b, embT, 16384, 1024, 768, 1, 0, 0, 0,
                                   0.03608439182435161f, EPI_BF, x_b);

  // 3. xT[b] = x[b]^T
  transpose_b16<<<dim3(32, 64, 8), dim3(32, 8), 0, stream>>>(x_b, xT, 2048, 1024);

  // 4. gram[b] = x[b] @ x[b]^T / 1024 -> f16, symmetric (36 tiles/batch)
  gram_sym<<<288, 512, 0, stream>>>(x_b, gram);

  // 5. weights = softmax(gram) -> bf16
  softmax_rows<<<16384, 256, 0, stream>>>(gram, wts);

  // 6. attn[b] = weights[b] @ x[b] -> bf16
  gemm_bt<<<256, 512, 0, stream>>>(wts, xT, 2048, 1024, 2048, 8,
                                   2048L * 2048, 1024L * 2048, 2048L * 1024,
                                   1.0f, EPI_BF, attn_b);

  // 7. post = LN(x + attn) -> bf16
  ln_residual_bb<<<16384, 256, 0, stream>>>(x_b, attn_b, post_b);

  // 8. FFN
  gemm_bt<<<256, 512, 0, stream>>>(post_b, W1T, 16384, 1024, 1024, 1, 0, 0, 0,
                                   0.03125f, EPI_RELUBF, hrelu);
  gemm_bt<<<256, 512, 0, stream>>>(hrelu, W2T, 16384, 1024, 1024, 1, 0, 0, 0,
                                   0.03125f, EPI_BF, h2b);

  // 9. final LN + pooled readout
  ln_residual_dot<<<16384, 256, 0, stream>>>(h2b, post_b, readout, rowdot);
  reduce_out<<<8, 256, 0, stream>>>(rowdot, out);
}

// Round 11
// 359.772 us; speedup vs baseline: 1.2362x; 1.0241x over previous
//
#include <hip/hip_runtime.h>
#include <hip/hip_bf16.h>

typedef __bf16 bf16x8 __attribute__((ext_vector_type(8)));
typedef float f32x4 __attribute__((ext_vector_type(4)));

__device__ __forceinline__ unsigned short f2bf(float f) {
  union { float f; unsigned u; } x; x.f = f;
  unsigned r = x.u + 0x7fffu + ((x.u >> 16) & 1u);
  return (unsigned short)(r >> 16);
}
__device__ __forceinline__ float bf2f(unsigned short u) {
  union { unsigned u; float f; } x; x.u = (unsigned)u << 16;
  return x.f;
}
__device__ __forceinline__ unsigned short f2h(float f) {
  union { _Float16 h; unsigned short u; } x; x.h = (_Float16)f;
  return x.u;
}
__device__ __forceinline__ float h2f(unsigned short u) {
  union { _Float16 h; unsigned short u; } x; x.u = u;
  return (float)x.h;
}

__device__ __forceinline__ void async_ld16(const void* g, void* l) {
  __builtin_amdgcn_global_load_lds(
      (__attribute__((address_space(1))) void*)const_cast<void*>(g),
      (__attribute__((address_space(3))) void*)l, 16, 0, 0);
}

#define SB __builtin_amdgcn_sched_barrier(0)

#define EPI_F32    0
#define EPI_BF     1
#define EPI_RELUBF 2
#define EPI_F16    3

// ---- r7 GEMM (best measured): 256x256, 4-phase K-split, 2 gates/K-tile ----
// Used for attnV + FFN1 + FFN2. Ledger/swizzle verified rounds 7-10.
__global__ __launch_bounds__(512, 2) void gemm_bt(
    const unsigned short* __restrict__ A,   // [nb][M][K] bf16
    const unsigned short* __restrict__ Bt,  // [nb][N][K] bf16
    int M, int N, int K, int nbatch,
    long sA, long sB, long sC,
    float scale, int mode, void* __restrict__ outp)
{
  __shared__ unsigned short lds[65536];  // 128 KB
  const int t = threadIdx.x;
  const int w = t >> 6, l = t & 63;
  const int lr = l & 15, lg = l >> 4;
  const int wr = w >> 2, wc = w & 3;           // 2 M-waves x 4 N-waves
  const int ntn = N >> 8;
  const int tiles = (M >> 8) * ntn;
  const int chunk = (tiles * nbatch) >> 3;
  const int bid = blockIdx.x;
  const int wg = (bid & 7) * chunk + (bid >> 3);
  const int batch = wg / tiles;
  const int rem = wg - batch * tiles;
  const int row0 = (rem / ntn) << 8;
  const int col0 = (rem % ntn) << 8;

  const unsigned short* Ab  = A  + (long)batch * sA;
  const unsigned short* Btb = Bt + (long)batch * sB;

  const int ks = ((lg ^ ((lr >> 1) & 3)) << 3);
  const int srow = w * 16 + (l >> 2);
  const int kgo  = (((l & 3) ^ ((l >> 3) & 3)) << 3);
  const long aoff0 = (long)(row0 + srow) * K + kgo;
  const long boff0 = (long)(col0 + srow) * K + kgo;
  const long off128 = (long)K << 7;

  const int NT = K >> 6;

#define STAGEP(partE, base, kcol)                                      \
  { async_ld16((base) + (kcol),          &lds[(partE) + t * 8]);       \
    async_ld16((base) + off128 + (kcol), &lds[(partE) + 4096 + t * 8]); }

  f32x4 acc[8][4];
#pragma unroll
  for (int m = 0; m < 8; ++m)
#pragma unroll
    for (int n = 0; n < 4; ++n) acc[m][n] = (f32x4){0.f, 0.f, 0.f, 0.f};

  STAGEP(0,     Btb + boff0, 0);
  STAGEP(8192,  Ab + aoff0,  0);
  STAGEP(16384, Btb + boff0, 32);
  STAGEP(24576, Ab + aoff0,  32);
  SB;

  for (int tt = 0; tt < NT; ++tt) {
    const int bufe  = (tt & 1) << 15;
    const int nbufe = ((tt + 1) & 1) << 15;
    const bool st = (tt + 1) < NT;
    const int kn = (tt + 1) << 6;

#pragma unroll
    for (int kh = 0; kh < 2; ++kh) {
      if (kh == 0 || st) { asm volatile("s_waitcnt vmcnt(4)" ::: "memory"); }
      else               { asm volatile("s_waitcnt vmcnt(0)" ::: "memory"); }
      SB;
      __builtin_amdgcn_s_barrier();
      SB;

      const int pB = bufe + kh * 16384;
      const int pA = pB + 8192;

      bf16x8 bfr[4];
#pragma unroll
      for (int nf = 0; nf < 4; ++nf) {
        int rb = wc * 64 + nf * 16 + lr;
        bfr[nf] = *(const bf16x8*)&lds[pB + rb * 32 + ks];
      }
      {
        bf16x8 af[4];
#pragma unroll
        for (int i = 0; i < 4; ++i) {
          int ra = wr * 128 + i * 16 + lr;
          af[i] = *(const bf16x8*)&lds[pA + ra * 32 + ks];
        }
        if (st) STAGEP(nbufe + kh * 16384, Btb + boff0, kn + kh * 32);
        __builtin_amdgcn_s_setprio(1);
#pragma unroll
        for (int i = 0; i < 4; ++i)
#pragma unroll
          for (int nf = 0; nf < 4; ++nf)
            acc[i][nf] = __builtin_amdgcn_mfma_f32_16x16x32_bf16(af[i], bfr[nf], acc[i][nf], 0, 0, 0);
        __builtin_amdgcn_s_setprio(0);
      }
      {
        bf16x8 af[4];
#pragma unroll
        for (int i = 0; i < 4; ++i) {
          int ra = wr * 128 + 64 + i * 16 + lr;
          af[i] = *(const bf16x8*)&lds[pA + ra * 32 + ks];
        }
        if (st) STAGEP(nbufe + kh * 16384 + 8192, Ab + aoff0, kn + kh * 32);
        __builtin_amdgcn_s_setprio(1);
#pragma unroll
        for (int i = 0; i < 4; ++i)
#pragma unroll
          for (int nf = 0; nf < 4; ++nf)
            acc[4 + i][nf] = __builtin_amdgcn_mfma_f32_16x16x32_bf16(af[i], bfr[nf], acc[4 + i][nf], 0, 0, 0);
        __builtin_amdgcn_s_setprio(0);
      }
      SB;
    }
  }

  float* outF = (float*)outp;
  unsigned short* outH = (unsigned short*)outp;
  const size_t cb = (size_t)batch * (size_t)sC;
#pragma unroll
  for (int mf = 0; mf < 8; ++mf) {
    int rbase = row0 + wr * 128 + mf * 16 + lg * 4;
#pragma unroll
    for (int nf = 0; nf < 4; ++nf) {
      int c = col0 + wc * 64 + nf * 16 + lr;
      f32x4 v = acc[mf][nf];
#pragma unroll
      for (int q = 0; q < 4; ++q) {
        size_t idx = cb + (size_t)(rbase + q) * N + c;
        float val = v[q] * scale;
        if (mode == EPI_F32)         outF[idx] = val;
        else if (mode == EPI_BF)     outH[idx] = f2bf(val);
        else if (mode == EPI_RELUBF) outH[idx] = f2bf(fmaxf(val, 0.f));
        else                         outH[idx] = f2h(val);
      }
    }
  }
#undef STAGEP
}

// ---- g1_fused: x = seq(f32) @ embT^T * scale -> bf16. 256x256 tile, r7
// schedule, A reg-staged (f32 load -> f2bf -> ds_write_b128 to the identical
// linear LDS slots the async path used; B async unchanged).
// T14 split: A-loads of tile t+1 issued at (t,kh0); transform+write at end of
// (t,kh1). Ledger (A=8 reg-loads, B=4 async per tile): entry kh0: outstanding
// B(t)4 -> vmcnt(2) retires Bk0(t); entry kh1: Bk1(t)2+A(t+1)8+Bk0(t+1)2=12
// -> vmcnt(10) retires Bk1(t); tail kh1 vmcnt(0). Transform dep-wait retires
// A. lgkmcnt(0) at every gate publishes the ds_writes before the barrier.
__global__ __launch_bounds__(512, 2) void g1_fused(
    const float* __restrict__ A,            // [16384][768] f32
    const unsigned short* __restrict__ Bt,  // [1024][768] bf16
    float scale, unsigned short* __restrict__ outB)
{
  __shared__ unsigned short lds[65536];
  const int t = threadIdx.x;
  const int w = t >> 6, l = t & 63;
  const int lr = l & 15, lg = l >> 4;
  const int wr = w >> 2, wc = w & 3;
  const int K = 768;
  const int bid = blockIdx.x;
  const int wg = (bid & 7) * 32 + (bid >> 3);   // 256 tiles (64x4)
  const int row0 = (wg >> 2) << 8;
  const int col0 = (wg & 3) << 8;

  const int ks = ((lg ^ ((lr >> 1) & 3)) << 3);
  const int srow = w * 16 + (l >> 2);
  const int kgo  = (((l & 3) ^ ((l >> 3) & 3)) << 3);
  const long ar0 = (long)(row0 + srow) * K + kgo;
  const long ar1 = ar0 + (long)128 * K;
  const long boff0 = (long)(col0 + srow) * K + kgo;
  const long off128 = (long)K << 7;
  const int NT = 12;

#define STAGEB(partE, kcol)                                              \
  { async_ld16(Bt + boff0 + (kcol),          &lds[(partE) + t * 8]);     \
    async_ld16(Bt + boff0 + off128 + (kcol), &lds[(partE) + 4096 + t * 8]); }
#define WRA(partE, q0, q1, q2, q3)                                       \
  { uint4 pk;                                                            \
    pk.x = (unsigned)f2bf(q0.x) | ((unsigned)f2bf(q0.y) << 16);          \
    pk.y = (unsigned)f2bf(q0.z) | ((unsigned)f2bf(q0.w) << 16);          \
    pk.z = (unsigned)f2bf(q1.x) | ((unsigned)f2bf(q1.y) << 16);          \
    pk.w = (unsigned)f2bf(q1.z) | ((unsigned)f2bf(q1.w) << 16);          \
    *(uint4*)&lds[(partE) + t * 8] = pk;                                 \
    pk.x = (unsigned)f2bf(q2.x) | ((unsigned)f2bf(q2.y) << 16);          \
    pk.y = (unsigned)f2bf(q2.z) | ((unsigned)f2bf(q2.w) << 16);          \
    pk.z = (unsigned)f2bf(q3.x) | ((unsigned)f2bf(q3.y) << 16);          \
    pk.w = (unsigned)f2bf(q3.z) | ((unsigned)f2bf(q3.w) << 16);          \
    *(uint4*)&lds[(partE) + 4096 + t * 8] = pk; }

  f32x4 acc[8][4];
#pragma unroll
  for (int m = 0; m < 8; ++m)
#pragma unroll
    for (int n = 0; n < 4; ++n) acc[m][n] = (f32x4){0.f, 0.f, 0.f, 0.f};

  float4 ap0, ap1, ap2, ap3, ap4, ap5, ap6, ap7;
  // prologue: tile 0 — A via regs, B async
  ap0 = *(const float4*)&A[ar0];      ap1 = *(const float4*)&A[ar0 + 4];
  ap2 = *(const float4*)&A[ar1];      ap3 = *(const float4*)&A[ar1 + 4];
  ap4 = *(const float4*)&A[ar0 + 32]; ap5 = *(const float4*)&A[ar0 + 36];
  ap6 = *(const float4*)&A[ar1 + 32]; ap7 = *(const float4*)&A[ar1 + 36];
  STAGEB(0, 0);
  STAGEB(16384, 32);
  WRA(8192,  ap0, ap1, ap2, ap3);
  WRA(24576, ap4, ap5, ap6, ap7);
  SB;

  for (int tt = 0; tt < NT; ++tt) {
    const int bufe  = (tt & 1) << 15;
    const int nbufe = ((tt + 1) & 1) << 15;
    const bool st = (tt + 1) < NT;
    const int kn = (tt + 1) << 6;

#pragma unroll
    for (int kh = 0; kh < 2; ++kh) {
      if (kh == 0)  { asm volatile("s_waitcnt vmcnt(2) lgkmcnt(0)" ::: "memory"); }
      else if (st)  { asm volatile("s_waitcnt vmcnt(10) lgkmcnt(0)" ::: "memory"); }
      else          { asm volatile("s_waitcnt vmcnt(0) lgkmcnt(0)" ::: "memory"); }
      SB;
      __builtin_amdgcn_s_barrier();
      SB;

      const int pB = bufe + kh * 16384;
      const int pA = pB + 8192;

      bf16x8 bfr[4];
#pragma unroll
      for (int nf = 0; nf < 4; ++nf) {
        int rb = wc * 64 + nf * 16 + lr;
        bfr[nf] = *(const bf16x8*)&lds[pB + rb * 32 + ks];
      }
      {
        bf16x8 af[4];
#pragma unroll
        for (int i = 0; i < 4; ++i) {
          int ra = wr * 128 + i * 16 + lr;
          af[i] = *(const bf16x8*)&lds[pA + ra * 32 + ks];
        }
        if (kh == 0 && st) {
          ap0 = *(const float4*)&A[ar0 + kn];      ap1 = *(const float4*)&A[ar0 + kn + 4];
          ap2 = *(const float4*)&A[ar1 + kn];      ap3 = *(const float4*)&A[ar1 + kn + 4];
          ap4 = *(const float4*)&A[ar0 + kn + 32]; ap5 = *(const float4*)&A[ar0 + kn + 36];
          ap6 = *(const float4*)&A[ar1 + kn + 32]; ap7 = *(const float4*)&A[ar1 + kn + 36];
          STAGEB(nbufe + 0, kn);
        }
        __builtin_amdgcn_s_setprio(1);
#pragma unroll
        for (int i = 0; i < 4; ++i)
#pragma unroll
          for (int nf = 0; nf < 4; ++nf)
            acc[i][nf] = __builtin_amdgcn_mfma_f32_16x16x32_bf16(af[i], bfr[nf], acc[i][nf], 0, 0, 0);
        __builtin_amdgcn_s_setprio(0);
      }
      {
        bf16x8 af[4];
#pragma unroll
        for (int i = 0; i < 4; ++i) {
          int ra = wr * 128 + 64 + i * 16 + lr;
          af[i] = *(const bf16x8*)&lds[pA + ra * 32 + ks];
        }
        if (kh == 1 && st) STAGEB(nbufe + 16384, kn + 32);
        __builtin_amdgcn_s_setprio(1);
#pragma unroll
        for (int i = 0; i < 4; ++i)
#pragma unroll
          for (int nf = 0; nf < 4; ++nf)
            acc[4 + i][nf] = __builtin_amdgcn_mfma_f32_16x16x32_bf16(af[i], bfr[nf], acc[4 + i][nf], 0, 0, 0);
        __builtin_amdgcn_s_setprio(0);
        if (kh == 1 && st) {
          WRA(nbufe + 8192,  ap0, ap1, ap2, ap3);
          WRA(nbufe + 24576, ap4, ap5, ap6, ap7);
        }
      }
      SB;
    }
  }

#pragma unroll
  for (int mf = 0; mf < 8; ++mf) {
    int rbase = row0 + wr * 128 + mf * 16 + lg * 4;
#pragma unroll
    for (int nf = 0; nf < 4; ++nf) {
      int c = col0 + wc * 64 + nf * 16 + lr;
      f32x4 v = acc[mf][nf];
#pragma unroll
      for (int q = 0; q < 4; ++q)
        outB[(size_t)(rbase + q) * 1024 + c] = f2bf(v[q] * scale);
    }
  }
#undef STAGEB
#undef WRA
}

// ---- gram_sym2: gram[b] = x[b] @ x[b]^T / 1024 -> f16, triangular with
// 128x256 tiles (72/batch, grid 576) to fix the 256^2 makespan (288 blocks at
// 1 block/CU = 2 full rounds). 8 waves 2Mx4N, per-wave 64x64, acc[4][4].
// LDS 96KB: 2 dbuf x {Bk0 16K, Ak0 8K, Bk1 16K, Ak1 8K}. Stage 1 part/phase:
// (kh0,mh0) Bk0, (kh0,mh1) Ak0, (kh1,mh0) Bk1, (kh1,mh1) Ak1 (3 loads/kh).
// Gates at kh entries: vmcnt(3) (outstanding = other kh-pair's 3), tail
// vmcnt(0). Coverage: tiles j>=i>>1; mirror-write all tiles (identical values
// near diagonal, benign double-writes); proven complete.
__global__ __launch_bounds__(512, 2) void gram_sym2(
    const unsigned short* __restrict__ X,   // [8][2048][1024] bf16
    unsigned short* __restrict__ outH)      // [8][2048][2048] f16
{
  __shared__ unsigned short lds[49152];  // 96 KB
  const int t = threadIdx.x;
  const int w = t >> 6, l = t & 63;
  const int lr = l & 15, lg = l >> 4;
  const int wr = w >> 2, wc = w & 3;     // 2 M-waves x 4 N-waves
  const int bid = blockIdx.x;
  const int wg = (bid & 7) * 72 + (bid >> 3);
  const int batch = wg / 72;
  int f = wg - batch * 72;
  int bi = 0;
  while (f >= 8 - (bi >> 1)) { f -= 8 - (bi >> 1); ++bi; }
  const int bj = (bi >> 1) + f;
  const int row0 = bi << 7;              // 128-row tile
  const int col0 = bj << 8;              // 256-col tile

  const unsigned short* Xb = X + (long)batch * 2048 * 1024;

  const int ks = ((lg ^ ((lr >> 1) & 3)) << 3);
  // B staging (r7 formula): rows col0+srow, col0+srow+128
  const int srow = w * 16 + (l >> 2);
  const int kgoB = (((l & 3) ^ ((l >> 3) & 3)) << 3);
  const long boff0 = (long)(col0 + srow) * 1024 + kgoB;
  const long off128 = 1024L << 7;
  // A staging (r9 formula): row t>>2 (0..127), 1 load
  const long arow = (long)(row0 + (t >> 2)) * 1024 + (((t & 3) ^ ((t >> 3) & 3)) << 3);

#define STAGEB2(partE, kcol)                                              \
  { async_ld16(Xb + boff0 + (kcol),          &lds[(partE) + t * 8]);      \
    async_ld16(Xb + boff0 + off128 + (kcol), &lds[(partE) + 4096 + t * 8]); }
#define STAGEA2(partE, kcol)                                              \
  { async_ld16(Xb + arow + (kcol), &lds[(partE) + t * 8]); }

  f32x4 acc[4][4];
#pragma unroll
  for (int m = 0; m < 4; ++m)
#pragma unroll
    for (int n = 0; n < 4; ++n) acc[m][n] = (f32x4){0.f, 0.f, 0.f, 0.f};

  // buffer layout (elems): Bk0@0, Ak0@8192, Bk1@12288, Ak1@20480; stride 24576
  STAGEB2(0, 0);
  STAGEA2(8192, 0);
  STAGEB2(12288, 32);
  STAGEA2(20480, 32);
  SB;

  for (int tt = 0; tt < 16; ++tt) {
    const int bufe  = (tt & 1) * 24576;
    const int nbufe = ((tt + 1) & 1) * 24576;
    const bool st = (tt + 1) < 16;
    const int kn = (tt + 1) << 6;

#pragma unroll
    for (int kh = 0; kh < 2; ++kh) {
      if (kh == 0 || st) { asm volatile("s_waitcnt vmcnt(3)" ::: "memory"); }
      else               { asm volatile("s_waitcnt vmcnt(0)" ::: "memory"); }
      SB;
      __builtin_amdgcn_s_barrier();
      SB;

      const int pB = bufe + kh * 12288;
      const int pA = pB + 8192;

      bf16x8 bfr[4];
#pragma unroll
      for (int nf = 0; nf < 4; ++nf) {
        int rb = wc * 64 + nf * 16 + lr;
        bfr[nf] = *(const bf16x8*)&lds[pB + rb * 32 + ks];
      }
#pragma unroll
      for (int mh = 0; mh < 2; ++mh) {
        bf16x8 af[2];
#pragma unroll
        for (int i = 0; i < 2; ++i) {
          int ra = wr * 64 + mh * 32 + i * 16 + lr;
          af[i] = *(const bf16x8*)&lds[pA + ra * 32 + ks];
        }
        if (st) {
          if (mh == 0) { if (kh == 0) STAGEB2(nbufe + 0, kn) else STAGEB2(nbufe + 12288, kn + 32) }
          else         { if (kh == 0) STAGEA2(nbufe + 8192, kn) else STAGEA2(nbufe + 20480, kn + 32) }
        }
        __builtin_amdgcn_s_setprio(1);
#pragma unroll
        for (int i = 0; i < 2; ++i)
#pragma unroll
          for (int nf = 0; nf < 4; ++nf)
            acc[mh * 2 + i][nf] = __builtin_amdgcn_mfma_f32_16x16x32_bf16(af[i], bfr[nf], acc[mh * 2 + i][nf], 0, 0, 0);
        __builtin_amdgcn_s_setprio(0);
      }
      SB;
    }
  }

  unsigned short* ob = outH + (size_t)batch * 2048 * 2048;
  const float scale = 1.0f / 1024.0f;
#pragma unroll
  for (int am = 0; am < 4; ++am) {
    int rbase = row0 + wr * 64 + (am >> 1) * 32 + (am & 1) * 16 + lg * 4;
#pragma unroll
    for (int nf = 0; nf < 4; ++nf) {
      int c = col0 + wc * 64 + nf * 16 + lr;
      f32x4 v = acc[am][nf];
      unsigned short h0 = f2h(v[0] * scale), h1 = f2h(v[1] * scale);
      unsigned short h2 = f2h(v[2] * scale), h3 = f2h(v[3] * scale);
      ob[(size_t)(rbase + 0) * 2048 + c] = h0;
      ob[(size_t)(rbase + 1) * 2048 + c] = h1;
      ob[(size_t)(rbase + 2) * 2048 + c] = h2;
      ob[(size_t)(rbase + 3) * 2048 + c] = h3;
      ushort4 m4 = {h0, h1, h2, h3};
      *(ushort4*)&ob[(size_t)c * 2048 + rbase] = m4;
    }
  }
#undef STAGEB2
#undef STAGEA2
}

// ---------------- elementwise / reduction kernels ----------------

__device__ __forceinline__ float wave_sum(float v) {
#pragma unroll
  for (int o = 32; o; o >>= 1) v += __shfl_xor(v, o, 64);
  return v;
}
__device__ __forceinline__ float wave_max(float v) {
#pragma unroll
  for (int o = 32; o; o >>= 1) v = fmaxf(v, __shfl_xor(v, o, 64));
  return v;
}

__global__ __launch_bounds__(256) void transpose_cast(const float* __restrict__ in,
                                                      unsigned short* __restrict__ out,
                                                      int R, int C) {
  __shared__ float tile[32][33];
  int c0 = blockIdx.x * 32, r0 = blockIdx.y * 32;
  int tx = threadIdx.x, ty = threadIdx.y;  // block (32,8)
  for (int i = ty; i < 32; i += 8) tile[i][tx] = in[(size_t)(r0 + i) * C + c0 + tx];
  __syncthreads();
  for (int i = ty; i < 32; i += 8) out[(size_t)(c0 + i) * R + r0 + tx] = f2bf(tile[tx][i]);
}

__global__ __launch_bounds__(256) void transpose_b16(const unsigned short* __restrict__ in,
                                                     unsigned short* __restrict__ out,
                                                     int R, int C) {
  __shared__ unsigned short tile[32][33];
  int c0 = blockIdx.x * 32, r0 = blockIdx.y * 32;
  size_t zb = (size_t)blockIdx.z * R * C;
  int tx = threadIdx.x, ty = threadIdx.y;  // block (32,8)
  for (int i = ty; i < 32; i += 8) tile[i][tx] = in[zb + (size_t)(r0 + i) * C + c0 + tx];
  __syncthreads();
  for (int i = ty; i < 32; i += 8) out[zb + (size_t)(c0 + i) * R + r0 + tx] = tile[tx][i];
}

__global__ __launch_bounds__(256) void softmax_rows(const unsigned short* __restrict__ g,
                                                    unsigned short* __restrict__ wout) {
  __shared__ float red[4];
  int row = blockIdx.x, t = threadIdx.x;
  const unsigned short* gr = g + ((size_t)row << 11) + t * 8;
  ushort4 ua = *(const ushort4*)gr;
  ushort4 ub = *(const ushort4*)(gr + 4);
  float a0 = h2f(ua.x), a1 = h2f(ua.y), a2 = h2f(ua.z), a3 = h2f(ua.w);
  float b0 = h2f(ub.x), b1 = h2f(ub.y), b2 = h2f(ub.z), b3 = h2f(ub.w);
  float mx = fmaxf(fmaxf(fmaxf(a0, a1), fmaxf(a2, a3)),
                   fmaxf(fmaxf(b0, b1), fmaxf(b2, b3)));
  mx = wave_max(mx);
  if ((t & 63) == 0) red[t >> 6] = mx;
  __syncthreads();
  mx = fmaxf(fmaxf(red[0], red[1]), fmaxf(red[2], red[3]));
  float e0 = __expf(a0 - mx), e1 = __expf(a1 - mx), e2 = __expf(a2 - mx), e3 = __expf(a3 - mx);
  float e4 = __expf(b0 - mx), e5 = __expf(b1 - mx), e6 = __expf(b2 - mx), e7 = __expf(b3 - mx);
  float s = ((e0 + e1) + (e2 + e3)) + ((e4 + e5) + (e6 + e7));
  s = wave_sum(s);
  __syncthreads();
  if ((t & 63) == 0) red[t >> 6] = s;
  __syncthreads();
  s = (red[0] + red[1]) + (red[2] + red[3]);
  float inv = 1.0f / s;
  ushort4 o0, o1;
  o0.x = f2bf(e0 * inv); o0.y = f2bf(e1 * inv); o0.z = f2bf(e2 * inv); o0.w = f2bf(e3 * inv);
  o1.x = f2bf(e4 * inv); o1.y = f2bf(e5 * inv); o1.z = f2bf(e6 * inv); o1.w = f2bf(e7 * inv);
  size_t base = ((size_t)row << 11) + t * 8;
  *(ushort4*)&wout[base] = o0;
  *(ushort4*)&wout[base + 4] = o1;
}

// post = LN(x_b + attn_b), both bf16
__global__ __launch_bounds__(256) void ln_residual_bb(const unsigned short* __restrict__ xb,
                                                      const unsigned short* __restrict__ ab,
                                                      unsigned short* __restrict__ outB) {
  __shared__ float red[4];
  int row = blockIdx.x, t = threadIdx.x;
  size_t base = ((size_t)row << 10) + t * 4;
  ushort4 ua = *(const ushort4*)&xb[base];
  ushort4 ub = *(const ushort4*)&ab[base];
  float4 v = {bf2f(ua.x) + bf2f(ub.x), bf2f(ua.y) + bf2f(ub.y),
              bf2f(ua.z) + bf2f(ub.z), bf2f(ua.w) + bf2f(ub.w)};
  float s = (v.x + v.y) + (v.z + v.w);
  float ss = (v.x * v.x + v.y * v.y) + (v.z * v.z + v.w * v.w);
  s = wave_sum(s);
  if ((t & 63) == 0) red[t >> 6] = s;
  __syncthreads();
  s = (red[0] + red[1]) + (red[2] + red[3]);
  ss = wave_sum(ss);
  __syncthreads();
  if ((t & 63) == 0) red[t >> 6] = ss;
  __syncthreads();
  ss = (red[0] + red[1]) + (red[2] + red[3]);
  float mean = s * (1.0f / 1024.0f);
  float var = (ss - s * mean) * (1.0f / 1023.0f);
  float rstd = rsqrtf(var);
  ushort4 ob;
  ob.x = f2bf((v.x - mean) * rstd); ob.y = f2bf((v.y - mean) * rstd);
  ob.z = f2bf((v.z - mean) * rstd); ob.w = f2bf((v.w - mean) * rstd);
  *(ushort4*)&outB[base] = ob;
}

__global__ __launch_bounds__(256) void ln_residual_dot(const unsigned short* __restrict__ h2,
                                                       const unsigned short* __restrict__ post,
                                                       const float* __restrict__ readout,
                                                       float* __restrict__ rowdot) {
  __shared__ float red[4];
  int row = blockIdx.x, t = threadIdx.x;
  size_t base = ((size_t)row << 10) + t * 4;
  ushort4 ua = *(const ushort4*)&h2[base];
  ushort4 ub = *(const ushort4*)&post[base];
  float4 v = {bf2f(ua.x) + bf2f(ub.x), bf2f(ua.y) + bf2f(ub.y),
              bf2f(ua.z) + bf2f(ub.z), bf2f(ua.w) + bf2f(ub.w)};
  float s = (v.x + v.y) + (v.z + v.w);
  float ss = (v.x * v.x + v.y * v.y) + (v.z * v.z + v.w * v.w);
  s = wave_sum(s);
  if ((t & 63) == 0) red[t >> 6] = s;
  __syncthreads();
  s = (red[0] + red[1]) + (red[2] + red[3]);
  ss = wave_sum(ss);
  __syncthreads();
  if ((t & 63) == 0) red[t >> 6] = ss;
  __syncthreads();
  ss = (red[0] + red[1]) + (red[2] + red[3]);
  float mean = s * (1.0f / 1024.0f);
  float var = (ss - s * mean) * (1.0f / 1023.0f);
  float rstd = rsqrtf(var);
  float4 r = *(const float4*)&readout[t * 4];
  float dot = (v.x - mean) * rstd * r.x + (v.y - mean) * rstd * r.y +
              (v.z - mean) * rstd * r.z + (v.w - mean) * rstd * r.w;
  dot = wave_sum(dot);
  __syncthreads();
  if ((t & 63) == 0) red[t >> 6] = dot;
  __syncthreads();
  if (t == 0) rowdot[row] = (red[0] + red[1]) + (red[2] + red[3]);
}

__global__ __launch_bounds__(256) void reduce_out(const float* __restrict__ rowdot,
                                                  float* __restrict__ out) {
  __shared__ float red[4];
  int b = blockIdx.x, t = threadIdx.x;
  float s = 0.f;
  for (int i = t; i < 2048; i += 256) s += rowdot[(size_t)b * 2048 + i];
  s = wave_sum(s);
  if ((t & 63) == 0) red[t >> 6] = s;
  __syncthreads();
  if (t == 0) out[b] = ((red[0] + red[1]) + (red[2] + red[3])) * (1.0f / 65536.0f);
}

extern "C" void kernel_launch(void* const* d_in, const int* in_sizes, int n_in,
                              void* d_out, int out_size, void* d_ws, size_t ws_size,
                              hipStream_t stream) {
  const float* seq     = (const float*)d_in[0];  // [8,2048,768]
  const float* emb     = (const float*)d_in[1];  // [768,1024]
  const float* W1      = (const float*)d_in[2];  // [1024,1024]
  const float* W2      = (const float*)d_in[3];  // [1024,1024]
  const float* readout = (const float*)d_in[4];  // [1024]
  float* out = (float*)d_out;                    // [8]

  char* ws = (char*)d_ws;
  const size_t MB = 1024u * 1024u;
  // aliased layout (verified rounds 3-10; seq_b removed):
  unsigned short* x_b    = (unsigned short*)(ws + 0);        // 32MB [G1..LN1]
  unsigned short* h2b    = (unsigned short*)(ws + 0);        // 32MB [FFN2..LN2]
  unsigned short* xT     = (unsigned short*)(ws + 32 * MB);  // 32MB [tr..attnV]
  unsigned short* hrelu  = (unsigned short*)(ws + 32 * MB);  // 32MB [FFN1..FFN2]
  unsigned short* gram   = (unsigned short*)(ws + 64 * MB);  // 64MB f16 [gram..sm]
  unsigned short* attn_b = (unsigned short*)(ws + 64 * MB);  // 32MB bf16 [aV..LN1]
  unsigned short* wts    = (unsigned short*)(ws + 128 * MB); // 64MB [sm..attnV]
  unsigned short* post_b = (unsigned short*)(ws + 128 * MB); // 32MB [LN1..LN2]
  unsigned short* embT   = (unsigned short*)(ws + 216 * MB);
  unsigned short* W1T    = (unsigned short*)(ws + 218 * MB);
  unsigned short* W2T    = (unsigned short*)(ws + 220 * MB);
  float*          rowdot = (float*)(ws + 222 * MB);

  // 1. weight transposes (bf16)
  transpose_cast<<<dim3(32, 24), dim3(32, 8), 0, stream>>>(emb, embT, 768, 1024);
  transpose_cast<<<dim3(32, 32), dim3(32, 8), 0, stream>>>(W1, W1T, 1024, 1024);
  transpose_cast<<<dim3(32, 32), dim3(32, 8), 0, stream>>>(W2, W2T, 1024, 1024);

  // 2. x = seq @ emb / sqrt(768) -> bf16 (fused f32 cast; grid 256)
  g1_fused<<<256, 512, 0, stream>>>(seq, embT, 0.03608439182435161f, x_b);

  // 3. xT[b] = x[b]^T
  transpose_b16<<<dim3(32, 64, 8), dim3(32, 8), 0, stream>>>(x_b, xT, 2048, 1024);

  // 4. gram[b] = x[b] @ x[b]^T / 1024 -> f16, triangular 128x256 tiles
  gram_sym2<<<576, 512, 0, stream>>>(x_b, gram);

  // 5. weights = softmax(gram) -> bf16
  softmax_rows<<<16384, 256, 0, stream>>>(gram, wts);

  // 6. attn[b] = weights[b] @ x[b] -> bf16
  gemm_bt<<<256, 512, 0, stream>>>(wts, xT, 2048, 1024, 2048, 8,
                                   2048L * 2048, 1024L * 2048, 2048L * 1024,
                                   1.0f, EPI_BF, attn_b);

  // 7. post = LN(x + attn) -> bf16
  ln_residual_bb<<<16384, 256, 0, stream>>>(x_b, attn_b, post_b);

  // 8. FFN
  gemm_bt<<<256, 512, 0, stream>>>(post_b, W1T, 16384, 1024, 1024, 1, 0, 0, 0,
                                   0.03125f, EPI_RELUBF, hrelu);
  gemm_bt<<<256, 512, 0, stream>>>(hrelu, W2T, 16384, 1024, 1024, 1, 0, 0, 0,
                                   0.03125f, EPI_BF, h2b);

  // 9. final LN + pooled readout
  ln_residual_dot<<<16384, 256, 0, stream>>>(h2b, post_b, readout, rowdot);
  reduce_out<<<8, 256, 0, stream>>>(rowdot, out);
}